// Round 1
// baseline (336.454 us; speedup 1.0000x reference)
//
#include <hip/hip_runtime.h>

// ============================================================================
// Same algebraic collapse as before (layers 2..11 + head are linear; A commutes
// with W):  out = A^10 x1 w~ + sum_l gamma_l A^(9-l) 1 + b_out.
// NEW: everything runs in ONE persistent kernel (80 blocks, co-resident) with a
// custom device-scope grid barrier. 26 dispatches -> 2 (memset + kernel).
// The serial weight chain (10 matvecs) overlaps the CSR build phases; feature
// aggregation lives in registers; Horner uses 2 threads/node.
// ============================================================================

#define N_NODES 10000
#define N_EDGES 160000
#define DEPTH   10

#define NB      80                // blocks; <=256 CUs so all are co-resident
#define NTH     (NB * 256)        // 20480 threads (>= 2*N_NODES for pair-split)
#define NWAVES  (NTH / 64)        // 320 waves
#define RWAVES  (NWAVES - 4)      // 316 chain waves (block 0 reserved)

// ---- device-scope grid barrier (monotone generation; state zeroed per launch)
__device__ __forceinline__ void gbar(int* cnt, int* gen, int phase) {
    __syncthreads();
    if (threadIdx.x == 0) {
        __threadfence();  // release: write back L2 so other XCDs see our data
        int prev = __hip_atomic_fetch_add(cnt, 1, __ATOMIC_ACQ_REL,
                                          __HIP_MEMORY_SCOPE_AGENT);
        if (prev == NB * (phase + 1) - 1) {
            __hip_atomic_store(gen, phase + 1, __ATOMIC_RELEASE,
                               __HIP_MEMORY_SCOPE_AGENT);
        } else {
            while (__hip_atomic_load(gen, __ATOMIC_RELAXED,
                                     __HIP_MEMORY_SCOPE_AGENT) < phase + 1)
                __builtin_amdgcn_s_sleep(1);
        }
        __threadfence();  // acquire: invalidate L1/L2 so we see remote writes
    }
    __syncthreads();
}

// ---- one serial chain step: vout = Ws[l] @ vin ; gamma[l] = bs[l] . vin ----
__device__ __forceinline__ void chain_step(int s, int gw, int lane,
                                           const float* __restrict__ Ws,
                                           const float* __restrict__ bs,
                                           const float* __restrict__ W_out,
                                           float* __restrict__ vbufs,
                                           float* __restrict__ gamma) {
    if (gw < 4) return;  // block 0's waves do scan/pack instead
    const int l = 9 - s;
    const float* vin = (s == 0) ? W_out : (vbufs + (s & 1) * 512);
    float* vout = vbufs + ((s + 1) & 1) * 512;
    const float* W = Ws + (size_t)l * 512 * 512;
    const int w = gw - 4;  // 0..315
#pragma unroll
    for (int rr = 0; rr < 2; rr++) {
        int row = w + RWAVES * rr;
        if (row < 512) {
            const float* Wr = W + (size_t)row * 512;
            float acc = 0.f;
#pragma unroll
            for (int c = 0; c < 8; c++) acc += Wr[lane + 64 * c] * vin[lane + 64 * c];
#pragma unroll
            for (int off = 32; off; off >>= 1) acc += __shfl_xor(acc, off, 64);
            if (lane == 0) vout[row] = acc;
        }
    }
    if (gw == 255) {  // one spare wave also computes gamma[l] = b_l . vin
        const float* bl = bs + (size_t)l * 512;
        float acc = 0.f;
#pragma unroll
        for (int c = 0; c < 8; c++) acc += bl[lane + 64 * c] * vin[lane + 64 * c];
#pragma unroll
        for (int off = 32; off; off >>= 1) acc += __shfl_xor(acc, off, 64);
        if (lane == 0) gamma[l] = acc;
    }
}

extern "C" __global__ void __launch_bounds__(256, 1) gcn_mega(
    const float* __restrict__ features, const float* __restrict__ W_in,
    const float* __restrict__ b_in, const float* __restrict__ Ws,
    const float* __restrict__ bs, const float* __restrict__ W_out,
    const float* __restrict__ b_out, const int* __restrict__ src,
    const int* __restrict__ dst, float* __restrict__ out,
    int* bar_cnt, int* bar_gen, int* deg, int* row_ptr, int* cursor,
    int* esrc, float* vbufs, float* gamma, float* Wb,
    float* rb0, float* rb1)
{
    const int t    = blockIdx.x * 256 + threadIdx.x;   // 0..20479
    const int gw   = t >> 6;                           // global wave id
    const int lane = t & 63;
    int bp = 0;

    // ================= P0: count degrees  ||  chain l=9  ||  pack Wb ========
    for (int e = t; e < N_EDGES; e += NTH) atomicAdd(&deg[dst[e]], 1);
    if (blockIdx.x == 0) {
        // pack [512][8] rows: {Win col j (6), b_in[j], pad} for uniform loads
        for (int idx = threadIdx.x; idx < 4096; idx += 256) {
            int j = idx >> 3, k = idx & 7;
            float v = 0.f;
            if (k < 6) v = W_in[k * 512 + j];
            else if (k == 6) v = b_in[j];
            Wb[idx] = v;
        }
    }
    chain_step(0, gw, lane, Ws, bs, W_out, vbufs, gamma);
    gbar(bar_cnt, bar_gen, bp); bp++;

    // ================= P1: prefix scan (block 0)  ||  chain l=8 =============
    if (blockIdx.x == 0) {
        __shared__ int sums[256];
        const int tt = threadIdx.x;
        const int base = tt * 40;                      // 256*40 = 10240 >= N
        int ssum = 0;
#pragma unroll 8
        for (int i = 0; i < 40; i++) {
            int idx = base + i;
            ssum += (idx < N_NODES) ? deg[idx] : 0;
        }
        sums[tt] = ssum;
        __syncthreads();
        for (int off = 1; off < 256; off <<= 1) {
            int v = (tt >= off) ? sums[tt - off] : 0;
            __syncthreads();
            sums[tt] += v;
            __syncthreads();
        }
        int run = (tt > 0) ? sums[tt - 1] : 0;
        for (int i = 0; i < 40; i++) {
            int idx = base + i;
            if (idx < N_NODES) {
                row_ptr[idx] = run;
                cursor[idx]  = run;
                run += deg[idx];                       // L1-hot reload
            }
        }
        if (tt == 255) row_ptr[N_NODES] = run;
    }
    chain_step(1, gw, lane, Ws, bs, W_out, vbufs, gamma);
    gbar(bar_cnt, bar_gen, bp); bp++;

    // ================= P2: CSR fill  ||  chain l=7 ==========================
    for (int e = t; e < N_EDGES; e += NTH) {
        int d = dst[e];
        int pos = atomicAdd(&cursor[d], 1);
        esrc[pos] = src[e];
    }
    chain_step(2, gw, lane, Ws, bs, W_out, vbufs, gamma);
    gbar(bar_cnt, bar_gen, bp); bp++;

    // ================= P3: feature aggregation (in regs)  ||  chain l=6 =====
    const int node = t >> 1;       // 2 threads per node
    const int half = t & 1;
    int ns = 0, ne = 0;
    float a0 = 0.f, a1 = 0.f, a2 = 0.f, a3 = 0.f, a4 = 0.f, a5 = 0.f;
    if (node < N_NODES) {
        ns = row_ptr[node];
        ne = row_ptr[node + 1];
        for (int pp = ns + half; pp < ne; pp += 2) {
            int j = esrc[pp];
            const float2* f = (const float2*)(features + (size_t)j * 6);
            float2 f0 = f[0], f1 = f[1], f2 = f[2];
            a0 += f0.x; a1 += f0.y; a2 += f1.x;
            a3 += f1.y; a4 += f2.x; a5 += f2.y;
        }
        // pair-combine: both halves end with the full per-node sums
        a0 += __shfl_xor(a0, 1, 64);
        a1 += __shfl_xor(a1, 1, 64);
        a2 += __shfl_xor(a2, 1, 64);
        a3 += __shfl_xor(a3, 1, 64);
        a4 += __shfl_xor(a4, 1, 64);
        a5 += __shfl_xor(a5, 1, 64);
    }
    chain_step(3, gw, lane, Ws, bs, W_out, vbufs, gamma);
    gbar(bar_cnt, bar_gen, bp); bp++;

    // ================= P4..P9: chain tail l=5..0 (irreducibly serial) =======
    for (int s = 4; s <= 9; s++) {
        chain_step(s, gw, lane, Ws, bs, W_out, vbufs, gamma);
        gbar(bar_cnt, bar_gen, bp); bp++;
    }
    // vtilde = vbufs[0..511]; all gamma[0..9] final.

    // ================= P10: z = relu(a . W_in + b_in) . w~  -> rb0 ==========
    if (node < N_NODES) {
        const float4* Wb4 = (const float4*)Wb;
        const float* vt = vbufs;                       // vtilde
        float zacc = 0.f;
#pragma unroll 4
        for (int jj = 0; jj < 256; jj++) {
            int j = (jj << 1) | half;                  // pair splits j-range
            float4 wA = Wb4[2 * j];                    // w0..w3
            float4 wB = Wb4[2 * j + 1];                // w4, w5, b, pad
            float tv = wB.z + a0 * wA.x + a1 * wA.y + a2 * wA.z +
                       a3 * wA.w + a4 * wB.x + a5 * wB.y;
            zacc += fmaxf(tv, 0.f) * vt[j];
        }
        zacc += __shfl_xor(zacc, 1, 64);
        if (half == 0) rb0[node] = zacc;
    }
    gbar(bar_cnt, bar_gen, bp); bp++;

    // ================= P11..P20: Horner  r <- A r + gamma[l] ================
    for (int l = 0; l < DEPTH; l++) {
        if (node < N_NODES) {
            const float* rin = (l & 1) ? rb1 : rb0;
            float h0 = 0.f, h1 = 0.f;
            int pp = ns + half;
            for (; pp + 2 < ne; pp += 4) {
                h0 += rin[esrc[pp]];
                h1 += rin[esrc[pp + 2]];
            }
            if (pp < ne) h0 += rin[esrc[pp]];
            float hs = h0 + h1;
            hs += __shfl_xor(hs, 1, 64);
            if (half == 0) {
                float res = hs + gamma[l];
                if (l == DEPTH - 1) out[node] = res + b_out[0];
                else ((l & 1) ? rb0 : rb1)[node] = res;
            }
        }
        if (l < DEPTH - 1) { gbar(bar_cnt, bar_gen, bp); bp++; }
    }
}

// ---------------- launch ----------------

extern "C" void kernel_launch(void* const* d_in, const int* in_sizes, int n_in,
                              void* d_out, int out_size, void* d_ws, size_t ws_size,
                              hipStream_t stream) {
    const float* features = (const float*)d_in[0];  // [10000, 6]
    const float* W_in     = (const float*)d_in[1];  // [6, 512]
    const float* b_in     = (const float*)d_in[2];  // [512]
    const float* Ws       = (const float*)d_in[3];  // [10, 512, 512]
    const float* bs       = (const float*)d_in[4];  // [10, 512]
    const float* W_out    = (const float*)d_in[5];  // [512, 1]
    const float* b_out    = (const float*)d_in[6];  // [1]
    const int*   src      = (const int*)d_in[7];    // [160000]
    const int*   dst      = (const int*)d_in[8];    // [160000]
    float* out = (float*)d_out;                     // [10000]

    char* base = (char*)d_ws;
    int*   bar_cnt = (int*)(base + 0);
    int*   bar_gen = (int*)(base + 64);
    int*   deg     = (int*)(base + 128);      // 40000 B
    int*   row_ptr = (int*)(base + 40192);    // 40004 B
    int*   cursor  = (int*)(base + 80256);    // 40000 B
    int*   esrc    = (int*)(base + 120320);   // 640000 B
    float* vbufs   = (float*)(base + 760320); // 4096 B  (2 x 512)
    float* gamma   = (float*)(base + 764416); // 64 B
    float* Wb      = (float*)(base + 764480); // 16384 B ([512][8])
    float* rb0     = (float*)(base + 780864); // 40064 B
    float* rb1     = (float*)(base + 820928); // 40064 B

    // zero barrier state + deg every launch (captured in the graph => every replay)
    hipMemsetAsync(base, 0, 40128, stream);

    gcn_mega<<<NB, 256, 0, stream>>>(features, W_in, b_in, Ws, bs, W_out, b_out,
                                     src, dst, out,
                                     bar_cnt, bar_gen, deg, row_ptr, cursor,
                                     esrc, vbufs, gamma, Wb, rb0, rb1);
}

// Round 2
// 266.504 us; speedup vs baseline: 1.2625x; 1.2625x over previous
//
#include <hip/hip_runtime.h>

// ============================================================================
// Algebraic collapse (layers 2..11 + head linear; A commutes with W):
//   out = A^10 x1 w~ + sum_l gamma_l A^(9-l) 1 + b_out
// ONE persistent kernel (80 blocks). Round-2 change: the contended single-line
// RMW grid barrier (~12us each) is replaced by a distributed arrive-flag
// barrier (per-block private lines + block-0 gather + gen broadcast, no RMW).
// esrc edge slices are staged in LDS (immune to the per-barrier L1/L2
// invalidation); the prefix scan holds its 40 values in registers.
// ============================================================================

#define N_NODES 10000
#define N_EDGES 160000
#define DEPTH   10

#define NB      80                // blocks; all co-resident on 256 CUs
#define NTH     (NB * 256)        // 20480 threads
#define RWAVES  ((NTH / 64) - 4)  // 316 chain waves (block 0's 4 waves excluded)
#define NPB     125               // nodes per block: 80*125 = 10000 exactly
#define ECAP    4096              // LDS edge-slice capacity (exp 2000, +46 sigma)

// ---- distributed grid barrier: no same-line RMW anywhere -------------------
__device__ __forceinline__ void gbar(int* arrive, int* gen, int phase) {
    const int tx = threadIdx.x;
    const int target = phase + 1;
    __syncthreads();
    if (blockIdx.x == 0) {
        if (tx > 0 && tx < NB) {        // poll blocks 1..79, one flag per thread
            while (__hip_atomic_load(&arrive[tx * 32], __ATOMIC_RELAXED,
                                     __HIP_MEMORY_SCOPE_AGENT) < target)
                __builtin_amdgcn_s_sleep(1);
        }
        __syncthreads();
        if (tx == 0) {
            __threadfence();            // acquire remote data / release own
            __hip_atomic_store(gen, target, __ATOMIC_RELEASE,
                               __HIP_MEMORY_SCOPE_AGENT);
        }
        __syncthreads();
    } else {
        if (tx == 0) {
            __threadfence();            // release this block's writes
            __hip_atomic_store(&arrive[blockIdx.x * 32], target,
                               __ATOMIC_RELEASE, __HIP_MEMORY_SCOPE_AGENT);
            while (__hip_atomic_load(gen, __ATOMIC_RELAXED,
                                     __HIP_MEMORY_SCOPE_AGENT) < target)
                __builtin_amdgcn_s_sleep(1);
            __threadfence();            // acquire
        }
        __syncthreads();
    }
}

// ---- one serial chain step: vout = Ws[l] @ vin ; gamma[l] = bs[l] . vin ----
__device__ __forceinline__ void chain_step(int s, int gw, int lane,
                                           const float* __restrict__ Ws,
                                           const float* __restrict__ bs,
                                           const float* __restrict__ W_out,
                                           float* __restrict__ vbufs,
                                           float* __restrict__ gamma) {
    if (gw < 4) return;  // block 0's waves do scan/pack instead
    const int l = 9 - s;
    const float* vin = (s == 0) ? W_out : (vbufs + (s & 1) * 512);
    float* vout = vbufs + ((s + 1) & 1) * 512;
    const float* W = Ws + (size_t)l * 512 * 512;
    const int w = gw - 4;  // 0..315
#pragma unroll
    for (int rr = 0; rr < 2; rr++) {
        int row = w + RWAVES * rr;
        if (row < 512) {
            const float* Wr = W + (size_t)row * 512;
            float acc = 0.f;
#pragma unroll
            for (int c = 0; c < 8; c++) acc += Wr[lane + 64 * c] * vin[lane + 64 * c];
#pragma unroll
            for (int off = 32; off; off >>= 1) acc += __shfl_xor(acc, off, 64);
            if (lane == 0) vout[row] = acc;
        }
    }
    if (gw == 255) {  // one spare wave also computes gamma[l] = b_l . vin
        const float* bl = bs + (size_t)l * 512;
        float acc = 0.f;
#pragma unroll
        for (int c = 0; c < 8; c++) acc += bl[lane + 64 * c] * vin[lane + 64 * c];
#pragma unroll
        for (int off = 32; off; off >>= 1) acc += __shfl_xor(acc, off, 64);
        if (lane == 0) gamma[l] = acc;
    }
}

extern "C" __global__ void __launch_bounds__(256, 1) gcn_mega(
    const float* __restrict__ features, const float* __restrict__ W_in,
    const float* __restrict__ b_in, const float* __restrict__ Ws,
    const float* __restrict__ bs, const float* __restrict__ W_out,
    const float* __restrict__ b_out, const int* __restrict__ src,
    const int* __restrict__ dst, float* __restrict__ out,
    int* arrive, int* gen, int* deg, int* row_ptr, int* cursor,
    int* esrc, float* vbufs, float* gamma, float* Wb,
    float* rb0, float* rb1)
{
    __shared__ int lds_e[ECAP];
    __shared__ int s_info[2];

    const int tx   = threadIdx.x;
    const int bx   = blockIdx.x;
    const int t    = bx * 256 + tx;
    const int gw   = t >> 6;
    const int lane = t & 63;
    int bp = 0;

    // ================= P0: count degrees || pack Wb || chain s=0 ============
    for (int e = t; e < N_EDGES; e += NTH) atomicAdd(&deg[dst[e]], 1);
    if (bx == 0) {
        // pack [512][8] rows: {W_in col j (6), b_in[j], pad}
        for (int idx = tx; idx < 4096; idx += 256) {
            int j = idx >> 3, k = idx & 7;
            float v = 0.f;
            if (k < 6) v = W_in[k * 512 + j];
            else if (k == 6) v = b_in[j];
            Wb[idx] = v;
        }
    }
    chain_step(0, gw, lane, Ws, bs, W_out, vbufs, gamma);
    gbar(arrive, gen, bp); bp++;

    // ================= P1: prefix scan (block 0, in regs) || chain s=1 ======
    if (bx == 0) {
        __shared__ int sums[256];
        const int base = tx * 40;                 // 250 threads cover 10000
        const bool sact = base < N_NODES;
        int4 lv[10];
        int ssum = 0;
        if (sact) {
#pragma unroll
            for (int i = 0; i < 10; i++) {
                lv[i] = ((const int4*)deg)[tx * 10 + i];
                ssum += lv[i].x + lv[i].y + lv[i].z + lv[i].w;
            }
        }
        sums[tx] = ssum;
        __syncthreads();
        for (int off = 1; off < 256; off <<= 1) {
            int v = (tx >= off) ? sums[tx - off] : 0;
            __syncthreads();
            sums[tx] += v;
            __syncthreads();
        }
        if (sact) {
            int run = (tx > 0) ? sums[tx - 1] : 0;
#pragma unroll
            for (int i = 0; i < 10; i++) {
                int v0 = run;            run += lv[i].x;
                int v1 = run;            run += lv[i].y;
                int v2 = run;            run += lv[i].z;
                int v3 = run;            run += lv[i].w;
                int idx = base + i * 4;
                row_ptr[idx]     = v0;  cursor[idx]     = v0;
                row_ptr[idx + 1] = v1;  cursor[idx + 1] = v1;
                row_ptr[idx + 2] = v2;  cursor[idx + 2] = v2;
                row_ptr[idx + 3] = v3;  cursor[idx + 3] = v3;
            }
            if (tx == 249) row_ptr[N_NODES] = run;
        }
    }
    chain_step(1, gw, lane, Ws, bs, W_out, vbufs, gamma);
    gbar(arrive, gen, bp); bp++;

    // ================= P2: CSR fill || chain s=2 ============================
    for (int e = t; e < N_EDGES; e += NTH) {
        int d = dst[e];
        int pos = atomicAdd(&cursor[d], 1);
        esrc[pos] = src[e];
    }
    chain_step(2, gw, lane, Ws, bs, W_out, vbufs, gamma);
    gbar(arrive, gen, bp); bp++;

    // ================= P3: stage esrc slice -> LDS; aggregate || chain s=3 ==
    const int node = bx * NPB + (tx >> 1);        // always < 10000 when act
    const int half = tx & 1;
    const bool act = tx < 2 * NPB;                // 250 active threads
    if (tx == 0) {
        s_info[0] = row_ptr[bx * NPB];
        s_info[1] = row_ptr[bx * NPB + NPB];
    }
    __syncthreads();
    const int e_lo = s_info[0];
    const int slen = s_info[1] - e_lo;
    const bool use_lds = (slen <= ECAP);
    if (use_lds) {
        for (int i = tx; i < slen; i += 256) lds_e[i] = esrc[e_lo + i];
    }
    __syncthreads();

    int ns = 0, ne = 0;
    float a0 = 0.f, a1 = 0.f, a2 = 0.f, a3 = 0.f, a4 = 0.f, a5 = 0.f;
    if (act) {
        ns = row_ptr[node];
        ne = row_ptr[node + 1];
        if (use_lds) {
            for (int pp = ns + half; pp < ne; pp += 2) {
                int j = lds_e[pp - e_lo];
                const float2* f = (const float2*)(features + (size_t)j * 6);
                float2 f0 = f[0], f1 = f[1], f2 = f[2];
                a0 += f0.x; a1 += f0.y; a2 += f1.x;
                a3 += f1.y; a4 += f2.x; a5 += f2.y;
            }
        } else {
            for (int pp = ns + half; pp < ne; pp += 2) {
                int j = esrc[pp];
                const float2* f = (const float2*)(features + (size_t)j * 6);
                float2 f0 = f[0], f1 = f[1], f2 = f[2];
                a0 += f0.x; a1 += f0.y; a2 += f1.x;
                a3 += f1.y; a4 += f2.x; a5 += f2.y;
            }
        }
        a0 += __shfl_xor(a0, 1, 64);
        a1 += __shfl_xor(a1, 1, 64);
        a2 += __shfl_xor(a2, 1, 64);
        a3 += __shfl_xor(a3, 1, 64);
        a4 += __shfl_xor(a4, 1, 64);
        a5 += __shfl_xor(a5, 1, 64);
    }
    chain_step(3, gw, lane, Ws, bs, W_out, vbufs, gamma);
    gbar(arrive, gen, bp); bp++;

    // ================= P4..P9: chain tail s=4..9 (irreducibly serial) =======
    for (int s = 4; s <= 9; s++) {
        chain_step(s, gw, lane, Ws, bs, W_out, vbufs, gamma);
        gbar(arrive, gen, bp); bp++;
    }
    // vtilde = vbufs[0..511]; all gamma[0..9] final.

    // ================= P10: z = relu(a . W_in + b_in) . w~  -> rb0 ==========
    if (act) {
        const float4* Wb4 = (const float4*)Wb;
        const float* vt = vbufs;                   // vtilde
        float zacc = 0.f;
#pragma unroll 4
        for (int jj = 0; jj < 256; jj++) {
            int j = (jj << 1) | half;              // pair splits the j-range
            float4 wA = Wb4[2 * j];                // w0..w3
            float4 wB = Wb4[2 * j + 1];            // w4, w5, b, pad
            float tv = wB.z + a0 * wA.x + a1 * wA.y + a2 * wA.z +
                       a3 * wA.w + a4 * wB.x + a5 * wB.y;
            zacc += fmaxf(tv, 0.f) * vt[j];
        }
        zacc += __shfl_xor(zacc, 1, 64);
        if (half == 0) rb0[node] = zacc;
    }
    gbar(arrive, gen, bp); bp++;

    // ================= P11..P20: Horner  r <- A r + gamma[l] ================
    for (int l = 0; l < DEPTH; l++) {
        if (act) {
            const float* rin = (l & 1) ? rb1 : rb0;
            float h0 = 0.f, h1 = 0.f;
            int pp = ns + half;
            if (use_lds) {
                for (; pp + 2 < ne; pp += 4) {
                    h0 += rin[lds_e[pp - e_lo]];
                    h1 += rin[lds_e[pp + 2 - e_lo]];
                }
                if (pp < ne) h0 += rin[lds_e[pp - e_lo]];
            } else {
                for (; pp + 2 < ne; pp += 4) {
                    h0 += rin[esrc[pp]];
                    h1 += rin[esrc[pp + 2]];
                }
                if (pp < ne) h0 += rin[esrc[pp]];
            }
            float hs = h0 + h1;
            hs += __shfl_xor(hs, 1, 64);
            if (half == 0) {
                float res = hs + gamma[l];
                if (l == DEPTH - 1) out[node] = res + b_out[0];
                else ((l & 1) ? rb0 : rb1)[node] = res;
            }
        }
        if (l < DEPTH - 1) { gbar(arrive, gen, bp); bp++; }
    }
}

// ---------------- launch ----------------

extern "C" void kernel_launch(void* const* d_in, const int* in_sizes, int n_in,
                              void* d_out, int out_size, void* d_ws, size_t ws_size,
                              hipStream_t stream) {
    const float* features = (const float*)d_in[0];  // [10000, 6]
    const float* W_in     = (const float*)d_in[1];  // [6, 512]
    const float* b_in     = (const float*)d_in[2];  // [512]
    const float* Ws       = (const float*)d_in[3];  // [10, 512, 512]
    const float* bs       = (const float*)d_in[4];  // [10, 512]
    const float* W_out    = (const float*)d_in[5];  // [512, 1]
    const float* b_out    = (const float*)d_in[6];  // [1]
    const int*   src      = (const int*)d_in[7];    // [160000]
    const int*   dst      = (const int*)d_in[8];    // [160000]
    float* out = (float*)d_out;                     // [10000]

    char* base = (char*)d_ws;
    int*   arrive  = (int*)(base + 0);        // 80 * 128 B = 10240
    int*   gen     = (int*)(base + 10240);    // 128 B
    int*   deg     = (int*)(base + 10368);    // 40000 B   (memset ends at 50368)
    int*   row_ptr = (int*)(base + 50432);    // 40004 B
    int*   cursor  = (int*)(base + 90624);    // 40000 B
    int*   esrc    = (int*)(base + 130688);   // 640000 B
    float* vbufs   = (float*)(base + 770688); // 4096 B (2 x 512)
    float* gamma   = (float*)(base + 774784); // 64 B
    float* Wb      = (float*)(base + 774848); // 16384 B ([512][8])
    float* rb0     = (float*)(base + 791232); // 40064 B
    float* rb1     = (float*)(base + 831296); // 40064 B

    // zero barrier state + deg every launch (captured in graph => every replay)
    hipMemsetAsync(base, 0, 50368, stream);

    gcn_mega<<<NB, 256, 0, stream>>>(features, W_in, b_in, Ws, bs, W_out, b_out,
                                     src, dst, out,
                                     arrive, gen, deg, row_ptr, cursor,
                                     esrc, vbufs, gamma, Wb, rb0, rb1);
}

// Round 3
// 195.364 us; speedup vs baseline: 1.7222x; 1.3641x over previous
//
#include <hip/hip_runtime.h>

// ============================================================================
// Algebraic collapse (layers 2..11 + head linear; A commutes with W):
//   out = A^10 x1 w~ + sum_l gamma_l A^(9-l) 1 + b_out
// ONE persistent kernel (80 blocks x 512 threads). Round-3 change: NO
// __threadfence() anywhere (the per-XCD L2 wbl2+inv was ~8.5us/barrier).
// All cross-block data uses agent-scope relaxed atomics (sc1: L2-bypass,
// coherent at Infinity Cache). Barrier = per-wave s_waitcnt vmcnt(0) +
// __syncthreads + relaxed flag store + symmetric all-peer poll. Read-only
// inputs keep normal cached loads; per-block state lives in LDS.
// ============================================================================

#define N_NODES 10000
#define N_EDGES 160000
#define DEPTH   10

#define NB      80                 // blocks; all co-resident (<= 256 CUs)
#define BT      512                // threads per block
#define NTH     (NB * BT)          // 40960
#define NPB     125                // nodes per block: 80*125 = 10000 exactly
#define ECAP    4096               // LDS edge-slice capacity (exp ~2000)

// ---- agent-scope (device-coherent, L2-bypassing) scalar accessors ----------
__device__ __forceinline__ float ldA(const float* p) {
    return __hip_atomic_load(p, __ATOMIC_RELAXED, __HIP_MEMORY_SCOPE_AGENT);
}
__device__ __forceinline__ int ldAi(const int* p) {
    return __hip_atomic_load(p, __ATOMIC_RELAXED, __HIP_MEMORY_SCOPE_AGENT);
}
__device__ __forceinline__ void stA(float* p, float v) {
    __hip_atomic_store(p, v, __ATOMIC_RELAXED, __HIP_MEMORY_SCOPE_AGENT);
}
__device__ __forceinline__ void stAi(int* p, int v) {
    __hip_atomic_store(p, v, __ATOMIC_RELAXED, __HIP_MEMORY_SCOPE_AGENT);
}

// ---- fence-free symmetric grid barrier -------------------------------------
// Correctness: all cross-block stores are sc1 write-through; vmcnt(0) retire
// means "reached the coherence point", so flag-after-data ordering holds.
__device__ __forceinline__ void gbar(int* arrive, int phase) {
    const int tx = threadIdx.x;
    const int bx = blockIdx.x;
    const int target = phase + 1;
    asm volatile("s_waitcnt vmcnt(0)" ::: "memory");  // drain this wave's stores
    __syncthreads();                                  // (compiler drains others)
    if (tx == 0) stAi(&arrive[bx * 32], target);
    if (tx < NB && tx != bx) {
        while (ldAi(&arrive[tx * 32]) < target) __builtin_amdgcn_s_sleep(1);
    }
    __syncthreads();
}

// ---- one serial chain step: vout = Ws[l] @ vin ; gamma[l] = bs[l] . vin ----
__device__ __forceinline__ void chain_step(int s, int gw, int lane,
                                           const float* __restrict__ Ws,
                                           const float* __restrict__ bs,
                                           const float* __restrict__ W_out,
                                           float* __restrict__ vbufs,
                                           float* __restrict__ gamma) {
    const int w = gw - 8;          // block 0's 8 waves reserved for scan/etc.
    if (w < 0 || w > 512) return;  // rows 0..511 + one gamma wave (w==512)
    const int l = 9 - s;
    float vin[8];
    if (s == 0) {
#pragma unroll
        for (int c = 0; c < 8; c++) vin[c] = W_out[lane + 64 * c];  // read-only
    } else {
        const float* vb = vbufs + (s & 1) * 512;
#pragma unroll
        for (int c = 0; c < 8; c++) vin[c] = ldA(vb + lane + 64 * c);
    }
    float acc = 0.f;
    if (w < 512) {
        const float* Wr = Ws + (size_t)l * (512 * 512) + (size_t)w * 512;
#pragma unroll
        for (int c = 0; c < 8; c++) acc += Wr[lane + 64 * c] * vin[c];
    } else {
        const float* bl = bs + (size_t)l * 512;
#pragma unroll
        for (int c = 0; c < 8; c++) acc += bl[lane + 64 * c] * vin[c];
    }
#pragma unroll
    for (int off = 32; off; off >>= 1) acc += __shfl_xor(acc, off, 64);
    if (lane == 0) {
        if (w < 512) stA(vbufs + ((s + 1) & 1) * 512 + w, acc);
        else         stA(gamma + l, acc);
    }
}

extern "C" __global__ void __launch_bounds__(BT, 1) gcn_mega(
    const float* __restrict__ features, const float* __restrict__ W_in,
    const float* __restrict__ b_in, const float* __restrict__ Ws,
    const float* __restrict__ bs, const float* __restrict__ W_out,
    const float* __restrict__ b_out, const int* __restrict__ src,
    const int* __restrict__ dst, float* __restrict__ out,
    int* arrive, int* deg, int* row_ptr, int* cursor,
    int* esrc, float* vbufs, float* gamma, float* rb0, float* rb1)
{
    __shared__ int   lds_e[ECAP];    // 16 KB   edge slice (by-dst srcs)
    __shared__ float s_Wb[4096];     // 16 KB   [512][8]: {W_in col (6), b, pad}
    __shared__ float s_vt[512];      //  2 KB   vtilde
    __shared__ float s_gam[16];
    __shared__ int   s_info[2];
    __shared__ int   sums[BT];       //  2 KB   (block 0 scan)

    const int tx   = threadIdx.x;
    const int bx   = blockIdx.x;
    const int t    = bx * BT + tx;
    const int gw   = t >> 6;
    const int lane = t & 63;
    int bp = 0;

    // ================= P0: count degrees || per-block Wb pack || chain s=0 ==
    for (int e = t; e < N_EDGES; e += NTH) atomicAdd(&deg[dst[e]], 1);
    for (int idx = tx; idx < 4096; idx += BT) {
        int j = idx >> 3, k = idx & 7;
        float v = 0.f;
        if (k < 6) v = W_in[k * 512 + j];        // read-only: normal loads
        else if (k == 6) v = b_in[j];
        s_Wb[idx] = v;
    }
    chain_step(0, gw, lane, Ws, bs, W_out, vbufs, gamma);
    gbar(arrive, bp); bp++;

    // ================= P1: prefix scan (block 0, regs) || chain s=1 =========
    if (bx == 0) {
        const int base = tx * 20;                // 500 threads cover 10000
        const bool sact = base < N_NODES;
        int lv[20];
        int ssum = 0;
        if (sact) {
#pragma unroll
            for (int i = 0; i < 20; i++) { lv[i] = ldAi(&deg[base + i]); ssum += lv[i]; }
        }
        sums[tx] = ssum;
        __syncthreads();
        for (int off = 1; off < BT; off <<= 1) {
            int v = (tx >= off) ? sums[tx - off] : 0;
            __syncthreads();
            sums[tx] += v;
            __syncthreads();
        }
        if (sact) {
            int run = tx ? sums[tx - 1] : 0;
#pragma unroll
            for (int i = 0; i < 20; i++) {
                stAi(&row_ptr[base + i], run);
                stAi(&cursor[base + i], run);
                run += lv[i];
            }
            if (tx == 499) stAi(&row_ptr[N_NODES], run);
        }
    }
    chain_step(1, gw, lane, Ws, bs, W_out, vbufs, gamma);
    gbar(arrive, bp); bp++;

    // ================= P2: CSR fill || chain s=2 ============================
    for (int e = t; e < N_EDGES; e += NTH) {
        int d = dst[e];
        int sv = src[e];
        int pos = atomicAdd(&cursor[d], 1);
        stAi(&esrc[pos], sv);
    }
    chain_step(2, gw, lane, Ws, bs, W_out, vbufs, gamma);
    gbar(arrive, bp); bp++;

    // ================= P3: stage edge slice -> LDS; aggregate || chain s=3 ==
    if (tx == 0) {
        s_info[0] = ldAi(&row_ptr[bx * NPB]);
        s_info[1] = ldAi(&row_ptr[bx * NPB + NPB]);
    }
    __syncthreads();
    const int e_lo = s_info[0];
    const int slen = s_info[1] - e_lo;
    const bool use_lds = (slen <= ECAP);
    if (use_lds) {
        for (int i = tx; i < slen; i += BT) lds_e[i] = ldAi(&esrc[e_lo + i]);
    }
    __syncthreads();

    const int node = bx * NPB + (tx >> 2);   // 4 threads per node
    const int sub  = tx & 3;
    const bool act = tx < 4 * NPB;           // 500 active threads
    int ns = 0, ne = 0;
    float a0 = 0.f, a1 = 0.f, a2 = 0.f, a3 = 0.f, a4 = 0.f, a5 = 0.f;
    if (act) {
        ns = ldAi(&row_ptr[node]);
        ne = ldAi(&row_ptr[node + 1]);
        if (use_lds) {
            for (int pp = ns + sub; pp < ne; pp += 4) {
                int j = lds_e[pp - e_lo];
                const float2* f = (const float2*)(features + (size_t)j * 6);
                float2 f0 = f[0], f1 = f[1], f2 = f[2];
                a0 += f0.x; a1 += f0.y; a2 += f1.x;
                a3 += f1.y; a4 += f2.x; a5 += f2.y;
            }
        } else {
            for (int pp = ns + sub; pp < ne; pp += 4) {
                int j = ldAi(&esrc[pp]);
                const float2* f = (const float2*)(features + (size_t)j * 6);
                float2 f0 = f[0], f1 = f[1], f2 = f[2];
                a0 += f0.x; a1 += f0.y; a2 += f1.x;
                a3 += f1.y; a4 += f2.x; a5 += f2.y;
            }
        }
        a0 += __shfl_xor(a0, 1, 64); a0 += __shfl_xor(a0, 2, 64);
        a1 += __shfl_xor(a1, 1, 64); a1 += __shfl_xor(a1, 2, 64);
        a2 += __shfl_xor(a2, 1, 64); a2 += __shfl_xor(a2, 2, 64);
        a3 += __shfl_xor(a3, 1, 64); a3 += __shfl_xor(a3, 2, 64);
        a4 += __shfl_xor(a4, 1, 64); a4 += __shfl_xor(a4, 2, 64);
        a5 += __shfl_xor(a5, 1, 64); a5 += __shfl_xor(a5, 2, 64);
    }
    chain_step(3, gw, lane, Ws, bs, W_out, vbufs, gamma);
    gbar(arrive, bp); bp++;

    // ================= P4..P9: chain tail s=4..9 (irreducibly serial) =======
    for (int s = 4; s <= 9; s++) {
        chain_step(s, gw, lane, Ws, bs, W_out, vbufs, gamma);
        gbar(arrive, bp); bp++;
    }
    // vtilde = vbufs[0..511]; gamma[0..9] final.

    // ================= P10: z = relu(a.W_in + b_in) . w~  -> rb0 ============
    s_vt[tx & 511] = ldA(&vbufs[tx & 511]);      // 512 threads, one each
    if (tx < DEPTH) s_gam[tx] = ldA(&gamma[tx]);
    __syncthreads();
    if (act) {
        const float4* Wb4 = (const float4*)s_Wb;
        float zacc = 0.f;
#pragma unroll 4
        for (int jj = 0; jj < 128; jj++) {
            int j = (jj << 2) | sub;             // 4-way split of the j-range
            float4 wA = Wb4[2 * j];              // w0..w3
            float4 wB = Wb4[2 * j + 1];          // w4, w5, b, pad
            float tv = wB.z + a0 * wA.x + a1 * wA.y + a2 * wA.z +
                       a3 * wA.w + a4 * wB.x + a5 * wB.y;
            zacc += fmaxf(tv, 0.f) * s_vt[j];
        }
        zacc += __shfl_xor(zacc, 1, 64);
        zacc += __shfl_xor(zacc, 2, 64);
        if (sub == 0) stA(&rb0[node], zacc);
    }
    gbar(arrive, bp); bp++;

    // ================= P11..P20: Horner  r <- A r + gamma[l] ================
    for (int l = 0; l < DEPTH; l++) {
        if (act) {
            const float* rin = (l & 1) ? rb1 : rb0;
            float h0 = 0.f, h1 = 0.f;
            int pp = ns + sub;
            if (use_lds) {
                for (; pp + 4 < ne; pp += 8) {
                    h0 += ldA(&rin[lds_e[pp - e_lo]]);
                    h1 += ldA(&rin[lds_e[pp + 4 - e_lo]]);
                }
                if (pp < ne) h0 += ldA(&rin[lds_e[pp - e_lo]]);
            } else {
                for (; pp + 4 < ne; pp += 8) {
                    h0 += ldA(&rin[ldAi(&esrc[pp])]);
                    h1 += ldA(&rin[ldAi(&esrc[pp + 4])]);
                }
                if (pp < ne) h0 += ldA(&rin[ldAi(&esrc[pp])]);
            }
            float hs = h0 + h1;
            hs += __shfl_xor(hs, 1, 64);
            hs += __shfl_xor(hs, 2, 64);
            if (sub == 0) {
                float res = hs + s_gam[l];
                if (l == DEPTH - 1) out[node] = res + b_out[0];
                else stA(&((l & 1) ? rb0 : rb1)[node], res);
            }
        }
        if (l < DEPTH - 1) { gbar(arrive, bp); bp++; }
    }
}

// ---------------- launch ----------------

extern "C" void kernel_launch(void* const* d_in, const int* in_sizes, int n_in,
                              void* d_out, int out_size, void* d_ws, size_t ws_size,
                              hipStream_t stream) {
    const float* features = (const float*)d_in[0];  // [10000, 6]
    const float* W_in     = (const float*)d_in[1];  // [6, 512]
    const float* b_in     = (const float*)d_in[2];  // [512]
    const float* Ws       = (const float*)d_in[3];  // [10, 512, 512]
    const float* bs       = (const float*)d_in[4];  // [10, 512]
    const float* W_out    = (const float*)d_in[5];  // [512, 1]
    const float* b_out    = (const float*)d_in[6];  // [1]
    const int*   src      = (const int*)d_in[7];    // [160000]
    const int*   dst      = (const int*)d_in[8];    // [160000]
    float* out = (float*)d_out;                     // [10000]

    char* base = (char*)d_ws;
    int*   arrive  = (int*)(base + 0);        // 80 * 128 B = 10240
    int*   deg     = (int*)(base + 10240);    // 40000 B  (memset 0..50240)
    int*   row_ptr = (int*)(base + 50432);    // 40004 B
    int*   cursor  = (int*)(base + 90624);    // 40000 B
    int*   esrc    = (int*)(base + 130688);   // 640000 B
    float* vbufs   = (float*)(base + 770688); // 4096 B (2 x 512)
    float* gamma   = (float*)(base + 774784); // 64 B
    float* rb0     = (float*)(base + 774912); // 40000 B
    float* rb1     = (float*)(base + 814976); // 40000 B

    // zero barrier flags + deg each launch (captured in graph => every replay)
    hipMemsetAsync(base, 0, 50240, stream);

    gcn_mega<<<NB, BT, 0, stream>>>(features, W_in, b_in, Ws, bs, W_out, b_out,
                                    src, dst, out,
                                    arrive, deg, row_ptr, cursor,
                                    esrc, vbufs, gamma, rb0, rb1);
}

// Round 4
// 182.923 us; speedup vs baseline: 1.8393x; 1.0680x over previous
//
#include <hip/hip_runtime.h>

// ============================================================================
// Algebraic collapse (layers 2..11 + head linear; A commutes with W):
//   out = A^10 x1 w~ + sum_l gamma_l A^(9-l) 1 + b_out
// Round-4: TWO asynchronous block groups with PRIVATE barrier domains.
//   graph group (40 blocks x 1024): deg -> scan -> CSR fill -> feature agg,
//     then waits on a one-shot rendezvous, then proj + 10 Horner steps.
//   chain group (33 blocks): 10 serial dense matvecs (1 row/wave) with private
//     33-block barriers; stores w~/gamma, flags rendezvous, and EXITS.
// Fence-free coherence (validated R3): all cross-block traffic via agent-scope
// relaxed atomics (sc1, coherent at Infinity Cache); per-wave vmcnt(0) drain
// before each flag store. No __threadfence anywhere.
// ============================================================================

#define N_NODES 10000
#define N_EDGES 160000
#define DEPTH   10

#define NB_G 40                  // graph blocks
#define NB_C 33                  // chain blocks (33*16 waves = 528 >= 513)
#define NB   (NB_G + NB_C)
#define BT   1024
#define NTHG (NB_G * BT)         // 40960 graph threads
#define NPB  250                 // nodes per graph block (40*250 = 10000)
#define ECAP 8192                // LDS edge-slice capacity (expected ~4000)

// ---- agent-scope (device-coherent, L2-bypassing) scalar accessors ----------
__device__ __forceinline__ float ldA(const float* p) {
    return __hip_atomic_load(p, __ATOMIC_RELAXED, __HIP_MEMORY_SCOPE_AGENT);
}
__device__ __forceinline__ int ldAi(const int* p) {
    return __hip_atomic_load(p, __ATOMIC_RELAXED, __HIP_MEMORY_SCOPE_AGENT);
}
__device__ __forceinline__ void stA(float* p, float v) {
    __hip_atomic_store(p, v, __ATOMIC_RELAXED, __HIP_MEMORY_SCOPE_AGENT);
}
__device__ __forceinline__ void stAi(int* p, int v) {
    __hip_atomic_store(p, v, __ATOMIC_RELAXED, __HIP_MEMORY_SCOPE_AGENT);
}

// ---- fence-free symmetric group barrier (n <= 1024 blocks) -----------------
__device__ __forceinline__ void group_bar(int* flags, int gi, int n, int target) {
    const int tx = threadIdx.x;
    asm volatile("s_waitcnt vmcnt(0)" ::: "memory");   // drain this wave's stores
    __syncthreads();                                   // all waves drained
    if (tx == 0) stAi(&flags[gi * 32], target);
    if (tx < n && tx != gi) {
        while (ldAi(&flags[tx * 32]) < target) __builtin_amdgcn_s_sleep(1);
    }
    __syncthreads();
}

extern "C" __global__ void __launch_bounds__(BT, 1) gcn_mega(
    const float* __restrict__ features, const float* __restrict__ W_in,
    const float* __restrict__ b_in, const float* __restrict__ Ws,
    const float* __restrict__ bs, const float* __restrict__ W_out,
    const float* __restrict__ b_out, const int* __restrict__ src,
    const int* __restrict__ dst, float* __restrict__ out,
    int* g_arrive, int* c_arrive, int* rdv, int* deg, int* row_ptr,
    int* cursor, int* esrc, float* vbufs, float* gamma,
    float* rb0, float* rb1)
{
    __shared__ int   lds_e[ECAP];     // 32 KB  edge slice
    __shared__ float s_Wb[4096];      // 16 KB  [512][8]: {W_in col (6), b, pad}
    __shared__ float s_vt[512];       //  2 KB  vtilde
    __shared__ float s_gam[16];
    __shared__ int   s_info[2];
    __shared__ int   s_wsum[16];

    const int tx = threadIdx.x;
    const int bx = blockIdx.x;

    // ======================= CHAIN GROUP (blocks >= NB_G) ===================
    if (bx >= NB_G) {
        const int gi   = bx - NB_G;                 // 0..32
        const int cw   = gi * (BT / 64) + (tx >> 6); // 0..527
        const int lane = tx & 63;
        for (int s = 0; s < DEPTH; s++) {
            const int l = 9 - s;
            if (cw <= 512) {
                float vin[8];
                if (s == 0) {
#pragma unroll
                    for (int c = 0; c < 8; c++) vin[c] = W_out[lane + 64 * c];
                } else {
                    const float* vb = vbufs + (s & 1) * 512;
#pragma unroll
                    for (int c = 0; c < 8; c++) vin[c] = ldA(vb + lane + 64 * c);
                }
                const float* rowp = (cw < 512)
                    ? (Ws + (size_t)l * (512 * 512) + (size_t)cw * 512)
                    : (bs + (size_t)l * 512);
                float acc = 0.f;
#pragma unroll
                for (int c = 0; c < 8; c++) acc += rowp[lane + 64 * c] * vin[c];
#pragma unroll
                for (int off = 32; off; off >>= 1) acc += __shfl_xor(acc, off, 64);
                if (lane == 0) {
                    if (cw < 512) stA(&vbufs[((s + 1) & 1) * 512 + cw], acc);
                    else          stA(&gamma[l], acc);
                }
            }
            if (s < DEPTH - 1) group_bar(c_arrive, gi, NB_C, s + 1);
        }
        // rendezvous: publish results and exit
        asm volatile("s_waitcnt vmcnt(0)" ::: "memory");
        __syncthreads();
        if (tx == 0) stAi(&rdv[gi * 32], 1);
        return;
    }

    // ======================= GRAPH GROUP (blocks < NB_G) ====================
    const int gi = bx;
    int gt = 1;

    // -------- P0: degree count + per-block W_in pack ------------------------
    {
        const int t0 = bx * BT + tx;
        for (int e = t0; e < N_EDGES; e += NTHG) atomicAdd(&deg[dst[e]], 1);
    }
    for (int idx = tx; idx < 4096; idx += BT) {
        int j = idx >> 3, k = idx & 7;
        float v = 0.f;
        if (k < 6) v = W_in[k * 512 + j];          // read-only: cached loads
        else if (k == 6) v = b_in[j];
        s_Wb[idx] = v;
    }
    group_bar(g_arrive, gi, NB_G, gt++);

    // -------- P1: prefix scan (graph block 0, shuffle-based) ----------------
    if (bx == 0) {
        const int lane = tx & 63, wid = tx >> 6;    // 16 waves
        const bool sact = tx < 1000;                // 1000 x 10 = 10000
        int lv[10];
        int ssum = 0;
        if (sact) {
#pragma unroll
            for (int i = 0; i < 10; i++) { lv[i] = ldAi(&deg[tx * 10 + i]); ssum += lv[i]; }
        }
        int v = ssum;                               // wave inclusive scan
#pragma unroll
        for (int off = 1; off < 64; off <<= 1) {
            int u = __shfl_up(v, off, 64);
            if (lane >= off) v += u;
        }
        if (lane == 63) s_wsum[wid] = v;
        __syncthreads();
        if (wid == 0) {                             // scan the 16 wave totals
            int w = (lane < 16) ? s_wsum[lane] : 0;
#pragma unroll
            for (int off = 1; off < 16; off <<= 1) {
                int u = __shfl_up(w, off, 64);
                if (lane >= off) w += u;
            }
            if (lane < 16) s_wsum[lane] = w;
        }
        __syncthreads();
        if (sact) {
            int run = (wid ? s_wsum[wid - 1] : 0) + (v - ssum);  // exclusive
#pragma unroll
            for (int i = 0; i < 10; i++) {
                stAi(&row_ptr[tx * 10 + i], run);
                stAi(&cursor[tx * 10 + i], run);
                run += lv[i];
            }
            if (tx == 999) stAi(&row_ptr[N_NODES], run);
        }
    }
    group_bar(g_arrive, gi, NB_G, gt++);

    // -------- P2: CSR fill --------------------------------------------------
    {
        const int t0 = bx * BT + tx;
        for (int e = t0; e < N_EDGES; e += NTHG) {
            int d = dst[e];
            int sv = src[e];
            int pos = atomicAdd(&cursor[d], 1);
            stAi(&esrc[pos], sv);
        }
    }
    group_bar(g_arrive, gi, NB_G, gt++);

    // -------- P3: stage edge slice -> LDS; aggregate features ---------------
    if (tx == 0) {
        s_info[0] = ldAi(&row_ptr[bx * NPB]);
        s_info[1] = ldAi(&row_ptr[bx * NPB + NPB]);
    }
    __syncthreads();
    const int e_lo = s_info[0];
    const int slen = s_info[1] - e_lo;
    const bool use_lds = (slen <= ECAP);
    if (use_lds) {
        for (int i = tx; i < slen; i += BT) lds_e[i] = ldAi(&esrc[e_lo + i]);
    }
    __syncthreads();

    const int node = bx * NPB + (tx >> 2);          // 4 threads/node
    const int sub  = tx & 3;
    const bool act = tx < 4 * NPB;                  // 1000 active threads
    int ns = 0, ne = 0;
    float a0 = 0.f, a1 = 0.f, a2 = 0.f, a3 = 0.f, a4 = 0.f, a5 = 0.f;
    if (act) {
        ns = ldAi(&row_ptr[node]);
        ne = ldAi(&row_ptr[node + 1]);
        if (use_lds) {
            for (int pp = ns + sub; pp < ne; pp += 4) {
                int j = lds_e[pp - e_lo];
                const float2* f = (const float2*)(features + (size_t)j * 6);
                float2 f0 = f[0], f1 = f[1], f2 = f[2];
                a0 += f0.x; a1 += f0.y; a2 += f1.x;
                a3 += f1.y; a4 += f2.x; a5 += f2.y;
            }
        } else {
            for (int pp = ns + sub; pp < ne; pp += 4) {
                int j = ldAi(&esrc[pp]);
                const float2* f = (const float2*)(features + (size_t)j * 6);
                float2 f0 = f[0], f1 = f[1], f2 = f[2];
                a0 += f0.x; a1 += f0.y; a2 += f1.x;
                a3 += f1.y; a4 += f2.x; a5 += f2.y;
            }
        }
        a0 += __shfl_xor(a0, 1, 64); a0 += __shfl_xor(a0, 2, 64);
        a1 += __shfl_xor(a1, 1, 64); a1 += __shfl_xor(a1, 2, 64);
        a2 += __shfl_xor(a2, 1, 64); a2 += __shfl_xor(a2, 2, 64);
        a3 += __shfl_xor(a3, 1, 64); a3 += __shfl_xor(a3, 2, 64);
        a4 += __shfl_xor(a4, 1, 64); a4 += __shfl_xor(a4, 2, 64);
        a5 += __shfl_xor(a5, 1, 64); a5 += __shfl_xor(a5, 2, 64);
    }

    // -------- rendezvous: wait for chain group (one-shot, read-only) --------
    if (tx < NB_C) {
        while (ldAi(&rdv[tx * 32]) < 1) __builtin_amdgcn_s_sleep(1);
    }
    __syncthreads();
    if (tx < 512) s_vt[tx] = ldA(&vbufs[tx]);       // w~ (chain final output)
    if (tx >= 512 && tx < 512 + DEPTH) s_gam[tx - 512] = ldA(&gamma[tx - 512]);
    __syncthreads();

    // -------- P10: z = relu(a . W_in + b_in) . w~  -> rb0 -------------------
    if (act) {
        const float4* Wb4 = (const float4*)s_Wb;
        float zacc = 0.f;
#pragma unroll 4
        for (int jj = 0; jj < 128; jj++) {
            int j = (jj << 2) | sub;                // 4-way split of j-range
            float4 wA = Wb4[2 * j];                 // w0..w3
            float4 wB = Wb4[2 * j + 1];             // w4, w5, b, pad
            float tv = wB.z + a0 * wA.x + a1 * wA.y + a2 * wA.z +
                       a3 * wA.w + a4 * wB.x + a5 * wB.y;
            zacc += fmaxf(tv, 0.f) * s_vt[j];
        }
        zacc += __shfl_xor(zacc, 1, 64);
        zacc += __shfl_xor(zacc, 2, 64);
        if (sub == 0) stA(&rb0[node], zacc);
    }
    group_bar(g_arrive, gi, NB_G, gt++);

    // -------- P11..P20: Horner  r <- A r + gamma[l] -------------------------
    for (int l = 0; l < DEPTH; l++) {
        if (act) {
            const float* rin = (l & 1) ? rb1 : rb0;
            float h0 = 0.f, h1 = 0.f;
            int pp = ns + sub;
            if (use_lds) {
                for (; pp + 4 < ne; pp += 8) {
                    h0 += ldA(&rin[lds_e[pp - e_lo]]);
                    h1 += ldA(&rin[lds_e[pp + 4 - e_lo]]);
                }
                if (pp < ne) h0 += ldA(&rin[lds_e[pp - e_lo]]);
            } else {
                for (; pp + 4 < ne; pp += 8) {
                    h0 += ldA(&rin[ldAi(&esrc[pp])]);
                    h1 += ldA(&rin[ldAi(&esrc[pp + 4])]);
                }
                if (pp < ne) h0 += ldA(&rin[ldAi(&esrc[pp])]);
            }
            float hs = h0 + h1;
            hs += __shfl_xor(hs, 1, 64);
            hs += __shfl_xor(hs, 2, 64);
            if (sub == 0) {
                float res = hs + s_gam[l];
                if (l == DEPTH - 1) out[node] = res + b_out[0];
                else stA(&((l & 1) ? rb0 : rb1)[node], res);
            }
        }
        if (l < DEPTH - 1) group_bar(g_arrive, gi, NB_G, gt++);
    }
}

// ---------------- launch ----------------

extern "C" void kernel_launch(void* const* d_in, const int* in_sizes, int n_in,
                              void* d_out, int out_size, void* d_ws, size_t ws_size,
                              hipStream_t stream) {
    const float* features = (const float*)d_in[0];  // [10000, 6]
    const float* W_in     = (const float*)d_in[1];  // [6, 512]
    const float* b_in     = (const float*)d_in[2];  // [512]
    const float* Ws       = (const float*)d_in[3];  // [10, 512, 512]
    const float* bs       = (const float*)d_in[4];  // [10, 512]
    const float* W_out    = (const float*)d_in[5];  // [512, 1]
    const float* b_out    = (const float*)d_in[6];  // [1]
    const int*   src      = (const int*)d_in[7];    // [160000]
    const int*   dst      = (const int*)d_in[8];    // [160000]
    float* out = (float*)d_out;                     // [10000]

    char* base = (char*)d_ws;
    int*   g_arrive = (int*)(base + 0);        // 40*128 B
    int*   c_arrive = (int*)(base + 5120);     // 40*128 B (33 used)
    int*   rdv      = (int*)(base + 10240);    // 40*128 B (33 used)
    int*   deg      = (int*)(base + 15360);    // 40000 B  (memset 0..55360)
    int*   row_ptr  = (int*)(base + 55424);    // 40004 B
    int*   cursor   = (int*)(base + 95488);    // 40000 B
    int*   esrc     = (int*)(base + 135552);   // 640000 B
    float* vbufs    = (float*)(base + 775552); // 4096 B (2 x 512)
    float* gamma    = (float*)(base + 779648); // 64 B
    float* rb0      = (float*)(base + 779712); // 40000 B
    float* rb1      = (float*)(base + 819712); // 40000 B

    // zero barrier/rendezvous flags + deg (captured in graph => every replay)
    hipMemsetAsync(base, 0, 55360, stream);

    gcn_mega<<<NB, BT, 0, stream>>>(features, W_in, b_in, Ws, bs, W_out, b_out,
                                    src, dst, out,
                                    g_arrive, c_arrive, rdv, deg, row_ptr,
                                    cursor, esrc, vbufs, gamma, rb0, rb1);
}